// Round 3
// baseline (312.286 us; speedup 1.0000x reference)
//
#include <hip/hip_runtime.h>
#include <math.h>

#define B_  4096
#define C_  64
#define LQ_ 32
#define D_  128
#define H_  192
#define NB_ 4   // b's per table block

typedef __attribute__((ext_vector_type(8))) short bf16x8;
typedef __attribute__((ext_vector_type(4))) float f32x4;

#define KEEP(x) asm volatile("" : "+v"(x))

__device__ inline unsigned cvt_pk_bf16(float lo, float hi) {
    unsigned r;
    asm("v_cvt_pk_bf16_f32 %0, %1, %2" : "=v"(r) : "v"(lo), "v"(hi));
    return r;
}
__device__ inline short f2b(float x) { return (short)(cvt_pk_bf16(x, x) & 0xffff); }
__device__ inline float sigm(float x) { return 1.f / (1.f + __expf(-x)); }

// ---------------------------------------------------------------------------
// Prep: transpose + convert weights to bf16.
// ---------------------------------------------------------------------------
__global__ __launch_bounds__(256) void prep_kernel(
    const float* __restrict__ W1, const float* __restrict__ W2,
    const float* __restrict__ Wx, const float* __restrict__ Wh,
    short* __restrict__ W1T, short* __restrict__ W2T, short* __restrict__ WTl)
{
    int idx = blockIdx.x * 256 + threadIdx.x;   // 0 .. 131071
    if (idx < 192 * 256) {
        int j = idx >> 8, k = idx & 255;
        W1T[idx] = f2b(W1[k * H_ + j]);
    }
    if (idx < 128 * 192) {
        int j = idx / 192, k = idx - j * 192;
        W2T[idx] = f2b(W2[k * D_ + j]);
    }
    if (idx < 512 * 256) {
        int p = idx >> 8, k = idx & 255;
        int w = p >> 6, g = (p >> 4) & 3, jj = p & 15;
        int jo = g * 128 + w * 16 + jj;
        float v = (k < 128) ? Wx[k * 512 + jo] : Wh[(k - 128) * 512 + jo];
        WTl[idx] = f2b(v);
    }
}

// ---------------------------------------------------------------------------
// Table encoder v2: grid 1024, 256 threads, NB_=4 b's per block.
// 32-row chunks, double GEMM per chunk, register prefetch of next chunk.
// Weights resident in VGPRs (pinned via KEEP).
// ---------------------------------------------------------------------------
__global__ __launch_bounds__(256, 2) void table_kernel(
    const float* __restrict__ header, const float* __restrict__ tword,
    const float* __restrict__ masks, const int* __restrict__ num_cols,
    const short* __restrict__ W1T, const float* __restrict__ b1,
    const short* __restrict__ W2T, const float* __restrict__ b2,
    float* __restrict__ te_out)
{
    const int bb  = blockIdx.x * NB_;
    const int tid = threadIdx.x;
    const int w   = tid >> 6;
    const int l   = tid & 63;
    const int lg  = l >> 4;
    const int ln  = l & 15;

    __shared__ __align__(16) short flat_s[32 * 256];  // 16 KB, swizzled
    __shared__ __align__(16) short h_s[32 * 192];     // 12 KB, swizzled
    __shared__ float msk[2][64];
    __shared__ float redv[128];
    __shared__ float redq[128];

    // ---- resident weights (pinned)
    bf16x8 bw1[3][8];
    float bias1[3];
    #pragma unroll
    for (int ct = 0; ct < 3; ++ct) {
        int j = w * 48 + ct * 16 + ln;
        bias1[ct] = b1[j];
        #pragma unroll
        for (int ks = 0; ks < 8; ++ks)
            bw1[ct][ks] = *(const bf16x8*)&W1T[j * 256 + ks * 32 + lg * 8];
    }
    bf16x8 bw2[2][6];
    float bias2[2];
    #pragma unroll
    for (int ct = 0; ct < 2; ++ct) {
        int j = w * 32 + ct * 16 + ln;
        bias2[ct] = b2[j];
        #pragma unroll
        for (int ks = 0; ks < 6; ++ks)
            bw2[ct][ks] = *(const bf16x8*)&W2T[j * 192 + ks * 32 + lg * 8];
    }
    #pragma unroll
    for (int ct = 0; ct < 3; ++ct) {
        KEEP(bias1[ct]);
        #pragma unroll
        for (int ks = 0; ks < 8; ++ks) KEEP(bw1[ct][ks]);
    }
    #pragma unroll
    for (int ct = 0; ct < 2; ++ct) {
        KEEP(bias2[ct]);
        #pragma unroll
        for (int ks = 0; ks < 6; ++ks) KEEP(bw2[ct][ks]);
    }

    // ---- prefetch machinery: 8 float4 per thread = one 32-row chunk
    float4 pf[8];
    const int pr = tid >> 6;            // base row group within chunk: idx>>6
    const int pc = tid & 63;            // float4-column 0..63
    auto issue = [&](int cc) {
        int b = bb + (cc >> 1);
        int row0 = (cc & 1) * 32;
        #pragma unroll
        for (int i = 0; i < 8; ++i) {
            int r = i * 4 + pr;          // (i*256+tid)>>6
            const float* src = (pc < 32)
                ? &header[((size_t)b * C_ + row0 + r) * D_ + pc * 4]
                : &tword [((size_t)b * C_ + row0 + r) * D_ + (pc - 32) * 4];
            pf[i] = *(const float4*)src;
        }
    };
    issue(0);

    float csum0 = 0.f, csum1 = 0.f;

    for (int cc = 0; cc < NB_ * 2; ++cc) {
        const int b    = bb + (cc >> 1);
        const int half = cc & 1;
        const int sb   = (cc >> 1) & 1;

        // ---- write prefetched chunk -> flat_s (bf16, swizzled)
        #pragma unroll
        for (int i = 0; i < 8; ++i) {
            int r = i * 4 + pr;
            uint2 p;
            p.x = cvt_pk_bf16(pf[i].x, pf[i].y);
            p.y = cvt_pk_bf16(pf[i].z, pf[i].w);
            *(uint2*)((char*)flat_s + r * 512 + ((pc * 8) ^ ((r & 7) << 4))) = p;
        }
        // ---- issue next chunk's loads (stay in flight across both GEMMs)
        if (cc + 1 < NB_ * 2) issue(cc + 1);
        // ---- mask for this b (ping-pong so prev b's GEMM2 is safe)
        if (half == 0 && tid < 64) msk[sb][tid] = masks[b * C_ + tid];
        __syncthreads();   // barrier1: flat_s ready

        // ---- GEMM1 (rows of this 32-chunk), h_s = relu(flat @ W1 + b1)
        #pragma unroll
        for (int rt = 0; rt < 2; ++rt) {
            int row = rt * 16 + ln;
            bf16x8 a[8];
            #pragma unroll
            for (int ks = 0; ks < 8; ++ks)
                a[ks] = *(const bf16x8*)((char*)flat_s + row * 512 +
                                         ((ks * 64 + lg * 16) ^ ((row & 7) << 4)));
            f32x4 acc[3];
            #pragma unroll
            for (int ct = 0; ct < 3; ++ct)
                acc[ct] = (f32x4){bias1[ct], bias1[ct], bias1[ct], bias1[ct]};
            #pragma unroll
            for (int ks = 0; ks < 8; ++ks)
                #pragma unroll
                for (int ct = 0; ct < 3; ++ct)
                    acc[ct] = __builtin_amdgcn_mfma_f32_16x16x32_bf16(a[ks], bw1[ct][ks], acc[ct], 0, 0, 0);
            #pragma unroll
            for (int ct = 0; ct < 3; ++ct) {
                int col = w * 48 + ct * 16 + ln;
                #pragma unroll
                for (int reg = 0; reg < 4; ++reg) {
                    int orow = rt * 16 + lg * 4 + reg;
                    *(short*)((char*)h_s + orow * 384 + ((col * 2) ^ ((orow & 7) << 4))) =
                        f2b(fmaxf(acc[ct][reg], 0.f));
                }
            }
        }
        __syncthreads();   // barrier2: h_s ready

        // ---- GEMM2 + fused mask*column-sum
        #pragma unroll
        for (int rt = 0; rt < 2; ++rt) {
            int row = rt * 16 + ln;
            bf16x8 a[6];
            #pragma unroll
            for (int ks = 0; ks < 6; ++ks)
                a[ks] = *(const bf16x8*)((char*)h_s + row * 384 +
                                         ((ks * 64 + lg * 16) ^ ((row & 7) << 4)));
            f32x4 acc2[2];
            #pragma unroll
            for (int ct = 0; ct < 2; ++ct)
                acc2[ct] = (f32x4){bias2[ct], bias2[ct], bias2[ct], bias2[ct]};
            #pragma unroll
            for (int ks = 0; ks < 6; ++ks)
                #pragma unroll
                for (int ct = 0; ct < 2; ++ct)
                    acc2[ct] = __builtin_amdgcn_mfma_f32_16x16x32_bf16(a[ks], bw2[ct][ks], acc2[ct], 0, 0, 0);
            #pragma unroll
            for (int reg = 0; reg < 4; ++reg) {
                int orow = rt * 16 + lg * 4 + reg;
                float m = msk[sb][half * 32 + orow];
                csum0 = fmaf(fmaxf(acc2[0][reg], 0.f), m, csum0);
                csum1 = fmaf(fmaxf(acc2[1][reg], 0.f), m, csum1);
            }
        }

        // ---- end of b: reduce, l2norm, store
        if (half == 1) {
            #pragma unroll
            for (int s = 16; s < 64; s <<= 1) {
                csum0 += __shfl_xor(csum0, s, 64);
                csum1 += __shfl_xor(csum1, s, 64);
            }
            float nc = (float)num_cols[b];
            if (l < 16) {
                redv[w * 32 + ln]      = csum0 / nc;
                redv[w * 32 + 16 + ln] = csum1 / nc;
            }
            __syncthreads();
            if (tid < 128) redq[tid] = redv[tid] * redv[tid];
            __syncthreads();
            for (int s = 64; s > 0; s >>= 1) {
                if (tid < s) redq[tid] += redq[tid + s];
                __syncthreads();
            }
            if (tid < 128) {
                float inv = rsqrtf(fmaxf(redq[0], 1e-12f));
                te_out[(size_t)b * D_ + tid] = redv[tid] * inv;
            }
            csum0 = 0.f; csum1 = 0.f;
        }
    }
}

// ---------------------------------------------------------------------------
// LSTM v2: 256 blocks x 512 threads, 16 rows/block. Weights pinned resident
// (128 VGPR); x_t prefetched one step ahead; one barrier per step.
// ---------------------------------------------------------------------------
__global__ __launch_bounds__(512, 2) void lstm_kernel(
    const float* __restrict__ q, const int* __restrict__ lengths,
    const short* __restrict__ WTl, const float* __restrict__ bl,
    float* __restrict__ qe_out)
{
    const int tid = threadIdx.x;
    const int b0  = blockIdx.x * 16;
    const int w   = tid >> 6;
    const int l   = tid & 63;
    const int lg  = l >> 4;
    const int ln  = l & 15;       // batch row within block
    const int d0  = w * 16 + lg * 4;

    __shared__ __align__(16) short xh[2][16 * 256];  // 2 x 8 KB, swizzled
    __shared__ float red8[8][16];

    // W fragments resident across all timesteps (pinned)
    bf16x8 wf[4][8];
    #pragma unroll
    for (int g = 0; g < 4; ++g)
        #pragma unroll
        for (int ks = 0; ks < 8; ++ks)
            wf[g][ks] = *(const bf16x8*)&WTl[(w * 64 + g * 16 + ln) * 256 + ks * 32 + lg * 8];
    float bias[4][4];
    #pragma unroll
    for (int g = 0; g < 4; ++g)
        #pragma unroll
        for (int reg = 0; reg < 4; ++reg)
            bias[g][reg] = bl[g * 128 + d0 + reg];
    #pragma unroll
    for (int g = 0; g < 4; ++g) {
        #pragma unroll
        for (int ks = 0; ks < 8; ++ks) KEEP(wf[g][ks]);
        #pragma unroll
        for (int reg = 0; reg < 4; ++reg) KEEP(bias[g][reg]);
    }

    float creg[4] = {0.f, 0.f, 0.f, 0.f};
    float hreg[4] = {0.f, 0.f, 0.f, 0.f};
    const int len = lengths[b0 + ln];
    const int sr = tid >> 5, sc = tid & 31;

    // prefetch x_0
    float4 qv = *(const float4*)&q[((size_t)(b0 + sr) * LQ_ + 0) * D_ + sc * 4];

    for (int t = 0; t < LQ_; ++t) {
        char* buf = (char*)xh[t & 1];
        // stage x_t from prefetched regs
        uint2 px; px.x = cvt_pk_bf16(qv.x, qv.y); px.y = cvt_pk_bf16(qv.z, qv.w);
        *(uint2*)(buf + sr * 512 + ((sc * 8) ^ ((sr & 7) << 4))) = px;
        // write h(t-1)
        uint2 ph; ph.x = cvt_pk_bf16(hreg[0], hreg[1]); ph.y = cvt_pk_bf16(hreg[2], hreg[3]);
        *(uint2*)(buf + ln * 512 + ((256 + d0 * 2) ^ ((ln & 7) << 4))) = ph;
        // prefetch x_{t+1} (in flight across barrier + MFMA)
        if (t + 1 < LQ_)
            qv = *(const float4*)&q[((size_t)(b0 + sr) * LQ_ + (t + 1)) * D_ + sc * 4];
        __syncthreads();

        bf16x8 xf[8];
        #pragma unroll
        for (int ks = 0; ks < 8; ++ks)
            xf[ks] = *(const bf16x8*)(buf + ln * 512 + ((ks * 64 + lg * 16) ^ ((ln & 7) << 4)));
        f32x4 acc[4];
        #pragma unroll
        for (int g = 0; g < 4; ++g)
            acc[g] = (f32x4){bias[g][0], bias[g][1], bias[g][2], bias[g][3]};
        #pragma unroll
        for (int ks = 0; ks < 8; ++ks)
            #pragma unroll
            for (int g = 0; g < 4; ++g)
                acc[g] = __builtin_amdgcn_mfma_f32_16x16x32_bf16(wf[g][ks], xf[ks], acc[g], 0, 0, 0);

        bool live = (t < len);
        #pragma unroll
        for (int reg = 0; reg < 4; ++reg) {
            float iv = sigm(acc[0][reg]);
            float fv = sigm(acc[1][reg]);
            float gv = fmaxf(acc[2][reg], 0.f);
            float ov = sigm(acc[3][reg]);
            float cn = fmaf(fv, creg[reg], iv * gv);
            float hn = ov * fmaxf(cn, 0.f);
            if (live) { creg[reg] = cn; hreg[reg] = hn; }
        }
    }

    // l2norm per batch row
    float sq = 0.f;
    #pragma unroll
    for (int reg = 0; reg < 4; ++reg) sq = fmaf(hreg[reg], hreg[reg], sq);
    sq += __shfl_xor(sq, 16, 64);
    sq += __shfl_xor(sq, 32, 64);
    if (l < 16) red8[w][ln] = sq;
    __syncthreads();
    float tot = 0.f;
    #pragma unroll
    for (int ww = 0; ww < 8; ++ww) tot += red8[ww][ln];
    float inv = rsqrtf(fmaxf(tot, 1e-12f));
    float4 o;
    o.x = hreg[0] * inv; o.y = hreg[1] * inv; o.z = hreg[2] * inv; o.w = hreg[3] * inv;
    *(float4*)&qe_out[(size_t)(b0 + ln) * D_ + d0] = o;
}

// ---------------------------------------------------------------------------
// Loss: 64 blocks x 64 threads, 1 sample per thread.
// ---------------------------------------------------------------------------
__global__ __launch_bounds__(64) void loss_kernel(
    const float* __restrict__ te, const float* __restrict__ qe,
    const float* __restrict__ labels, float* __restrict__ partial)
{
    const int tid = threadIdx.x;
    const int b   = blockIdx.x * 64 + tid;
    float dsum = 0.f;
    #pragma unroll 8
    for (int k4 = 0; k4 < 32; ++k4) {
        float4 a = *(const float4*)&qe[(size_t)b * D_ + k4 * 4];
        float4 c = *(const float4*)&te[(size_t)b * D_ + k4 * 4];
        float dx = a.x - c.x, dy = a.y - c.y, dz = a.z - c.z, dw = a.w - c.w;
        dsum += dx * dx + dy * dy + dz * dz + dw * dw;
    }
    float lab = labels[b];
    float ds  = sqrtf(dsum);
    float ml  = fmaxf(0.f, 1.f - ds);
    float loss = lab * dsum + (1.f - lab) * ml * ml;
    #pragma unroll
    for (int s = 32; s > 0; s >>= 1) loss += __shfl_xor(loss, s, 64);
    if (tid == 0) partial[blockIdx.x] = loss;
}

__global__ void final_kernel(const float* __restrict__ partial, float* __restrict__ out)
{
    const int tid = threadIdx.x;   // 64 threads
    float v = partial[tid];
    #pragma unroll
    for (int s = 32; s > 0; s >>= 1) v += __shfl_xor(v, s, 64);
    if (tid == 0) out[0] = 0.5f * v / (float)B_;
}

// ---------------------------------------------------------------------------
extern "C" void kernel_launch(void* const* d_in, const int* in_sizes, int n_in,
                              void* d_out, int out_size, void* d_ws, size_t ws_size,
                              hipStream_t stream)
{
    const float* q      = (const float*)d_in[0];
    const int*   qlen   = (const int*)d_in[1];
    const float* header = (const float*)d_in[2];
    const float* tword  = (const float*)d_in[3];
    const int*   ncols  = (const int*)d_in[4];
    const float* masks  = (const float*)d_in[5];
    const float* labels = (const float*)d_in[6];
    const float* W1     = (const float*)d_in[7];
    const float* b1     = (const float*)d_in[8];
    const float* W2     = (const float*)d_in[9];
    const float* b2     = (const float*)d_in[10];
    const float* Wx     = (const float*)d_in[11];
    const float* Wh     = (const float*)d_in[12];
    const float* bl     = (const float*)d_in[13];
    float* out = (float*)d_out;

    float* te      = (float*)d_ws;
    float* qe      = te + (size_t)B_ * D_;
    float* partial = qe + (size_t)B_ * D_;
    short* W1T     = (short*)(partial + 64);          // 192*256
    short* W2T     = W1T + 192 * 256;                 // 128*192
    short* WTl     = W2T + 128 * 192;                 // 512*256

    prep_kernel<<<512, 256, 0, stream>>>(W1, W2, Wx, Wh, W1T, W2T, WTl);
    table_kernel<<<B_ / NB_, 256, 0, stream>>>(header, tword, masks, ncols, W1T, b1, W2T, b2, te);
    lstm_kernel<<<B_ / 16, 512, 0, stream>>>(q, qlen, WTl, bl, qe);
    loss_kernel<<<B_ / 64, 64, 0, stream>>>(te, qe, labels, partial);
    final_kernel<<<1, 64, 0, stream>>>(partial, out);
}

// Round 4
// 166.748 us; speedup vs baseline: 1.8728x; 1.8728x over previous
//
#include <hip/hip_runtime.h>
#include <math.h>

#define B_  4096
#define C_  64
#define LQ_ 32
#define D_  128
#define H_  192

typedef __attribute__((ext_vector_type(8))) short bf16x8;
typedef __attribute__((ext_vector_type(4))) float f32x4;

#define KEEP(x) asm volatile("" : "+v"(x))

__device__ inline unsigned cvt_pk_bf16(float lo, float hi) {
    unsigned r;
    asm("v_cvt_pk_bf16_f32 %0, %1, %2" : "=v"(r) : "v"(lo), "v"(hi));
    return r;
}
__device__ inline short f2b(float x) { return (short)(cvt_pk_bf16(x, x) & 0xffff); }
__device__ inline float sigm(float x) { return 1.f / (1.f + __expf(-x)); }

// ---------------------------------------------------------------------------
// Prep: transpose + convert weights to bf16.
// ---------------------------------------------------------------------------
__global__ __launch_bounds__(256) void prep_kernel(
    const float* __restrict__ W1, const float* __restrict__ W2,
    const float* __restrict__ Wx, const float* __restrict__ Wh,
    short* __restrict__ W1T, short* __restrict__ W2T, short* __restrict__ WTl)
{
    int idx = blockIdx.x * 256 + threadIdx.x;   // 0 .. 131071
    if (idx < 192 * 256) {
        int j = idx >> 8, k = idx & 255;
        W1T[idx] = f2b(W1[k * H_ + j]);
    }
    if (idx < 128 * 192) {
        int j = idx / 192, k = idx - j * 192;
        W2T[idx] = f2b(W2[k * D_ + j]);
    }
    if (idx < 512 * 256) {
        int p = idx >> 8, k = idx & 255;
        int w = p >> 6, g = (p >> 4) & 3, jj = p & 15;
        int jo = g * 128 + w * 16 + jj;
        float v = (k < 128) ? Wx[k * 512 + jo] : Wh[(k - 128) * 512 + jo];
        WTl[idx] = f2b(v);
    }
}

// ---------------------------------------------------------------------------
// Table encoder v4: persistent blocks. grid 256 x 512 threads (8 waves),
// 16 b's per block, 32-row chunks (2 per b), double-buffered LDS stage,
// register prefetch of next chunk. Weights resident in VGPRs, pinned;
// amdgpu_waves_per_eu(2,2) gives the allocator the full 256-VGPR budget.
// Wave (wr = w>>2, ww = w&3): rows [wr*16..wr*16+16) of chunk,
// GEMM1 cols [ww*48..+48), GEMM2 cols [ww*32..+32).
// ---------------------------------------------------------------------------
__global__ __launch_bounds__(512) __attribute__((amdgpu_waves_per_eu(2, 2)))
void table_kernel(
    const float* __restrict__ header, const float* __restrict__ tword,
    const float* __restrict__ masks, const int* __restrict__ num_cols,
    const short* __restrict__ W1T, const float* __restrict__ b1,
    const short* __restrict__ W2T, const float* __restrict__ b2,
    float* __restrict__ te_out)
{
    const int bb0 = blockIdx.x * 16;
    const int tid = threadIdx.x;
    const int w   = tid >> 6;
    const int l   = tid & 63;
    const int lg  = l >> 4;
    const int ln  = l & 15;
    const int ww  = w & 3;
    const int wr  = w >> 2;

    __shared__ __align__(16) short flat_s[2][32 * 256];  // 2 x 16 KB, swizzled
    __shared__ __align__(16) short h_s[32 * 192];        // 12 KB, swizzled
    __shared__ float msk[64];
    __shared__ float redv[8][128];                       // 4 KB
    __shared__ float redq[2];

    // ---- resident weights (pinned; fits in 256-VGPR budget)
    bf16x8 bw1[3][8];
    float bias1[3];
    #pragma unroll
    for (int ct = 0; ct < 3; ++ct) {
        int j = ww * 48 + ct * 16 + ln;
        bias1[ct] = b1[j];
        #pragma unroll
        for (int ks = 0; ks < 8; ++ks)
            bw1[ct][ks] = *(const bf16x8*)&W1T[j * 256 + ks * 32 + lg * 8];
    }
    bf16x8 bw2[2][6];
    float bias2[2];
    #pragma unroll
    for (int ct = 0; ct < 2; ++ct) {
        int j = ww * 32 + ct * 16 + ln;
        bias2[ct] = b2[j];
        #pragma unroll
        for (int ks = 0; ks < 6; ++ks)
            bw2[ct][ks] = *(const bf16x8*)&W2T[j * 192 + ks * 32 + lg * 8];
    }
    #pragma unroll
    for (int ct = 0; ct < 3; ++ct) {
        KEEP(bias1[ct]);
        #pragma unroll
        for (int ks = 0; ks < 8; ++ks) KEEP(bw1[ct][ks]);
    }
    #pragma unroll
    for (int ct = 0; ct < 2; ++ct) {
        KEEP(bias2[ct]);
        #pragma unroll
        for (int ks = 0; ks < 6; ++ks) KEEP(bw2[ct][ks]);
    }

    // ---- prefetch: 4 float4 per thread = one 32-row fp32 chunk (32 KB)
    float4 pf[4];
    auto issue = [&](int cc) {
        int b    = bb0 + (cc >> 1);
        int row0 = (cc & 1) * 32;
        #pragma unroll
        for (int i = 0; i < 4; ++i) {
            int idx = i * 512 + tid;         // 0..2047 float4 slots
            int r   = idx >> 6;              // 0..31
            int c   = idx & 63;              // float4 col
            const float* src = (c < 32)
                ? &header[((size_t)b * C_ + row0 + r) * D_ + c * 4]
                : &tword [((size_t)b * C_ + row0 + r) * D_ + (c - 32) * 4];
            pf[i] = *(const float4*)src;
        }
    };
    issue(0);

    float csum0 = 0.f, csum1 = 0.f;

    for (int cc = 0; cc < 32; ++cc) {
        const int b    = bb0 + (cc >> 1);
        const int half = cc & 1;
        char* fbuf = (char*)flat_s[cc & 1];

        // (a) write prefetched chunk -> flat_s (bf16, swizzled)
        #pragma unroll
        for (int i = 0; i < 4; ++i) {
            int idx = i * 512 + tid;
            int r   = idx >> 6;
            int c   = idx & 63;
            uint2 p;
            p.x = cvt_pk_bf16(pf[i].x, pf[i].y);
            p.y = cvt_pk_bf16(pf[i].z, pf[i].w);
            *(uint2*)(fbuf + r * 512 + ((c * 8) ^ ((r & 7) << 4))) = p;
        }
        // (b) issue next chunk's loads (in flight across both GEMMs)
        if (cc + 1 < 32) issue(cc + 1);
        if (half == 0 && tid < 64) msk[tid] = masks[b * C_ + tid];
        __syncthreads();   // (c) flat ready

        // ---- GEMM1: rows wr*16+ln, cols ww*48..+48
        {
            int row = wr * 16 + ln;
            bf16x8 a[8];
            #pragma unroll
            for (int ks = 0; ks < 8; ++ks)
                a[ks] = *(const bf16x8*)(fbuf + row * 512 +
                                         ((ks * 64 + lg * 16) ^ ((row & 7) << 4)));
            f32x4 acc[3];
            #pragma unroll
            for (int ct = 0; ct < 3; ++ct)
                acc[ct] = (f32x4){bias1[ct], bias1[ct], bias1[ct], bias1[ct]};
            #pragma unroll
            for (int ks = 0; ks < 8; ++ks)
                #pragma unroll
                for (int ct = 0; ct < 3; ++ct)
                    acc[ct] = __builtin_amdgcn_mfma_f32_16x16x32_bf16(a[ks], bw1[ct][ks], acc[ct], 0, 0, 0);
            #pragma unroll
            for (int ct = 0; ct < 3; ++ct) {
                int col = ww * 48 + ct * 16 + ln;
                #pragma unroll
                for (int reg = 0; reg < 4; ++reg) {
                    int orow = wr * 16 + lg * 4 + reg;
                    *(short*)((char*)h_s + orow * 384 + ((col * 2) ^ ((orow & 7) << 4))) =
                        f2b(fmaxf(acc[ct][reg], 0.f));
                }
            }
        }
        __syncthreads();   // (e) h ready

        // ---- GEMM2 + fused mask*column-sum
        {
            int row = wr * 16 + ln;
            bf16x8 a[6];
            #pragma unroll
            for (int ks = 0; ks < 6; ++ks)
                a[ks] = *(const bf16x8*)((char*)h_s + row * 384 +
                                         ((ks * 64 + lg * 16) ^ ((row & 7) << 4)));
            f32x4 acc2[2];
            #pragma unroll
            for (int ct = 0; ct < 2; ++ct)
                acc2[ct] = (f32x4){bias2[ct], bias2[ct], bias2[ct], bias2[ct]};
            #pragma unroll
            for (int ks = 0; ks < 6; ++ks)
                #pragma unroll
                for (int ct = 0; ct < 2; ++ct)
                    acc2[ct] = __builtin_amdgcn_mfma_f32_16x16x32_bf16(a[ks], bw2[ct][ks], acc2[ct], 0, 0, 0);
            #pragma unroll
            for (int reg = 0; reg < 4; ++reg) {
                int crow = half * 32 + wr * 16 + lg * 4 + reg;
                float m = msk[crow];
                csum0 = fmaf(fmaxf(acc2[0][reg], 0.f), m, csum0);
                csum1 = fmaf(fmaxf(acc2[1][reg], 0.f), m, csum1);
            }
        }

        // ---- end of b: cross-wave reduce, l2norm, store
        if (half == 1) {
            #pragma unroll
            for (int s = 16; s < 64; s <<= 1) {
                csum0 += __shfl_xor(csum0, s, 64);
                csum1 += __shfl_xor(csum1, s, 64);
            }
            if (l < 16) {
                redv[w][ww * 32 + ln]      = csum0;
                redv[w][ww * 32 + 16 + ln] = csum1;
            }
            __syncthreads();
            float v = 0.f;
            if (tid < 128) {
                int j   = tid;
                int wwj = j >> 5;
                v = (redv[wwj][j] + redv[wwj + 4][j]) / (float)num_cols[b];
                float s = v * v;
                #pragma unroll
                for (int sh = 1; sh < 64; sh <<= 1) s += __shfl_xor(s, sh, 64);
                if (l == 0) redq[w] = s;
            }
            __syncthreads();
            if (tid < 128) {
                float inv = rsqrtf(fmaxf(redq[0] + redq[1], 1e-12f));
                te_out[(size_t)b * D_ + tid] = v * inv;
            }
            csum0 = 0.f; csum1 = 0.f;
            // redv/redq reuse for b+1 is separated by >=2 barriers (c),(e)
        }
    }
}

// ---------------------------------------------------------------------------
// LSTM v4: 256 blocks x 512 threads, 16 rows/block. Weights pinned resident
// (128 VGPR) with waves_per_eu(2,2) so they truly stay in registers.
// x_t prefetched one step ahead; one barrier per step.
// ---------------------------------------------------------------------------
__global__ __launch_bounds__(512) __attribute__((amdgpu_waves_per_eu(2, 2)))
void lstm_kernel(
    const float* __restrict__ q, const int* __restrict__ lengths,
    const short* __restrict__ WTl, const float* __restrict__ bl,
    float* __restrict__ qe_out)
{
    const int tid = threadIdx.x;
    const int b0  = blockIdx.x * 16;
    const int w   = tid >> 6;
    const int l   = tid & 63;
    const int lg  = l >> 4;
    const int ln  = l & 15;       // batch row within block
    const int d0  = w * 16 + lg * 4;

    __shared__ __align__(16) short xh[2][16 * 256];  // 2 x 8 KB, swizzled
    __shared__ float red8[8][16];

    // W fragments resident across all timesteps (pinned)
    bf16x8 wf[4][8];
    #pragma unroll
    for (int g = 0; g < 4; ++g)
        #pragma unroll
        for (int ks = 0; ks < 8; ++ks)
            wf[g][ks] = *(const bf16x8*)&WTl[(w * 64 + g * 16 + ln) * 256 + ks * 32 + lg * 8];
    float bias[4][4];
    #pragma unroll
    for (int g = 0; g < 4; ++g)
        #pragma unroll
        for (int reg = 0; reg < 4; ++reg)
            bias[g][reg] = bl[g * 128 + d0 + reg];
    #pragma unroll
    for (int g = 0; g < 4; ++g) {
        #pragma unroll
        for (int ks = 0; ks < 8; ++ks) KEEP(wf[g][ks]);
        #pragma unroll
        for (int reg = 0; reg < 4; ++reg) KEEP(bias[g][reg]);
    }

    float creg[4] = {0.f, 0.f, 0.f, 0.f};
    float hreg[4] = {0.f, 0.f, 0.f, 0.f};
    const int len = lengths[b0 + ln];
    const int sr = tid >> 5, sc = tid & 31;

    // prefetch x_0
    float4 qv = *(const float4*)&q[((size_t)(b0 + sr) * LQ_ + 0) * D_ + sc * 4];

    for (int t = 0; t < LQ_; ++t) {
        char* buf = (char*)xh[t & 1];
        // stage x_t from prefetched regs
        uint2 px; px.x = cvt_pk_bf16(qv.x, qv.y); px.y = cvt_pk_bf16(qv.z, qv.w);
        *(uint2*)(buf + sr * 512 + ((sc * 8) ^ ((sr & 7) << 4))) = px;
        // write h(t-1)
        uint2 ph; ph.x = cvt_pk_bf16(hreg[0], hreg[1]); ph.y = cvt_pk_bf16(hreg[2], hreg[3]);
        *(uint2*)(buf + ln * 512 + ((256 + d0 * 2) ^ ((ln & 7) << 4))) = ph;
        // prefetch x_{t+1} (in flight across barrier + MFMA)
        if (t + 1 < LQ_)
            qv = *(const float4*)&q[((size_t)(b0 + sr) * LQ_ + (t + 1)) * D_ + sc * 4];
        __syncthreads();

        bf16x8 xf[8];
        #pragma unroll
        for (int ks = 0; ks < 8; ++ks)
            xf[ks] = *(const bf16x8*)(buf + ln * 512 + ((ks * 64 + lg * 16) ^ ((ln & 7) << 4)));
        f32x4 acc[4];
        #pragma unroll
        for (int g = 0; g < 4; ++g)
            acc[g] = (f32x4){bias[g][0], bias[g][1], bias[g][2], bias[g][3]};
        #pragma unroll
        for (int ks = 0; ks < 8; ++ks)
            #pragma unroll
            for (int g = 0; g < 4; ++g)
                acc[g] = __builtin_amdgcn_mfma_f32_16x16x32_bf16(wf[g][ks], xf[ks], acc[g], 0, 0, 0);

        bool live = (t < len);
        #pragma unroll
        for (int reg = 0; reg < 4; ++reg) {
            float iv = sigm(acc[0][reg]);
            float fv = sigm(acc[1][reg]);
            float gv = fmaxf(acc[2][reg], 0.f);
            float ov = sigm(acc[3][reg]);
            float cn = fmaf(fv, creg[reg], iv * gv);
            float hn = ov * fmaxf(cn, 0.f);
            if (live) { creg[reg] = cn; hreg[reg] = hn; }
        }
    }

    // l2norm per batch row
    float sq = 0.f;
    #pragma unroll
    for (int reg = 0; reg < 4; ++reg) sq = fmaf(hreg[reg], hreg[reg], sq);
    sq += __shfl_xor(sq, 16, 64);
    sq += __shfl_xor(sq, 32, 64);
    if (l < 16) red8[w][ln] = sq;
    __syncthreads();
    float tot = 0.f;
    #pragma unroll
    for (int ww = 0; ww < 8; ++ww) tot += red8[ww][ln];
    float inv = rsqrtf(fmaxf(tot, 1e-12f));
    float4 o;
    o.x = hreg[0] * inv; o.y = hreg[1] * inv; o.z = hreg[2] * inv; o.w = hreg[3] * inv;
    *(float4*)&qe_out[(size_t)(b0 + ln) * D_ + d0] = o;
}

// ---------------------------------------------------------------------------
// Loss: 64 blocks x 64 threads, 1 sample per thread.
// ---------------------------------------------------------------------------
__global__ __launch_bounds__(64) void loss_kernel(
    const float* __restrict__ te, const float* __restrict__ qe,
    const float* __restrict__ labels, float* __restrict__ partial)
{
    const int tid = threadIdx.x;
    const int b   = blockIdx.x * 64 + tid;
    float dsum = 0.f;
    #pragma unroll 8
    for (int k4 = 0; k4 < 32; ++k4) {
        float4 a = *(const float4*)&qe[(size_t)b * D_ + k4 * 4];
        float4 c = *(const float4*)&te[(size_t)b * D_ + k4 * 4];
        float dx = a.x - c.x, dy = a.y - c.y, dz = a.z - c.z, dw = a.w - c.w;
        dsum += dx * dx + dy * dy + dz * dz + dw * dw;
    }
    float lab = labels[b];
    float ds  = sqrtf(dsum);
    float ml  = fmaxf(0.f, 1.f - ds);
    float loss = lab * dsum + (1.f - lab) * ml * ml;
    #pragma unroll
    for (int s = 32; s > 0; s >>= 1) loss += __shfl_xor(loss, s, 64);
    if (tid == 0) partial[blockIdx.x] = loss;
}

__global__ void final_kernel(const float* __restrict__ partial, float* __restrict__ out)
{
    const int tid = threadIdx.x;   // 64 threads
    float v = partial[tid];
    #pragma unroll
    for (int s = 32; s > 0; s >>= 1) v += __shfl_xor(v, s, 64);
    if (tid == 0) out[0] = 0.5f * v / (float)B_;
}

// ---------------------------------------------------------------------------
extern "C" void kernel_launch(void* const* d_in, const int* in_sizes, int n_in,
                              void* d_out, int out_size, void* d_ws, size_t ws_size,
                              hipStream_t stream)
{
    const float* q      = (const float*)d_in[0];
    const int*   qlen   = (const int*)d_in[1];
    const float* header = (const float*)d_in[2];
    const float* tword  = (const float*)d_in[3];
    const int*   ncols  = (const int*)d_in[4];
    const float* masks  = (const float*)d_in[5];
    const float* labels = (const float*)d_in[6];
    const float* W1     = (const float*)d_in[7];
    const float* b1     = (const float*)d_in[8];
    const float* W2     = (const float*)d_in[9];
    const float* b2     = (const float*)d_in[10];
    const float* Wx     = (const float*)d_in[11];
    const float* Wh     = (const float*)d_in[12];
    const float* bl     = (const float*)d_in[13];
    float* out = (float*)d_out;

    float* te      = (float*)d_ws;
    float* qe      = te + (size_t)B_ * D_;
    float* partial = qe + (size_t)B_ * D_;
    short* W1T     = (short*)(partial + 64);          // 192*256
    short* W2T     = W1T + 192 * 256;                 // 128*192
    short* WTl     = W2T + 128 * 192;                 // 512*256

    prep_kernel<<<512, 256, 0, stream>>>(W1, W2, Wx, Wh, W1T, W2T, WTl);
    table_kernel<<<B_ / 16, 512, 0, stream>>>(header, tword, masks, ncols, W1T, b1, W2T, b2, te);
    lstm_kernel<<<B_ / 16, 512, 0, stream>>>(q, qlen, WTl, bl, qe);
    loss_kernel<<<B_ / 64, 64, 0, stream>>>(te, qe, labels, partial);
    final_kernel<<<1, 64, 0, stream>>>(partial, out);
}

// Round 5
// 136.339 us; speedup vs baseline: 2.2905x; 1.2230x over previous
//
#include <hip/hip_runtime.h>
#include <math.h>

#define B_  4096
#define C_  64
#define LQ_ 32
#define D_  128
#define H_  192

typedef __attribute__((ext_vector_type(8))) short bf16x8;
typedef __attribute__((ext_vector_type(4))) float f32x4;

#define KEEP(x) asm volatile("" : "+v"(x))

__device__ inline unsigned cvt_pk_bf16(float lo, float hi) {
    unsigned r;
    asm("v_cvt_pk_bf16_f32 %0, %1, %2" : "=v"(r) : "v"(lo), "v"(hi));
    return r;
}
__device__ inline short f2b(float x) { return (short)(cvt_pk_bf16(x, x) & 0xffff); }
__device__ inline float sigm(float x) { return 1.f / (1.f + __expf(-x)); }

// Raw barrier: waits LDS ops only; leaves global loads in flight (T4).
__device__ inline void wg_barrier() {
    asm volatile("s_waitcnt lgkmcnt(0)" ::: "memory");
    __builtin_amdgcn_s_barrier();
    asm volatile("" ::: "memory");
}

// ---------------------------------------------------------------------------
// Prep: transpose + convert weights to bf16.
// ---------------------------------------------------------------------------
__global__ __launch_bounds__(256) void prep_kernel(
    const float* __restrict__ W1, const float* __restrict__ W2,
    const float* __restrict__ Wx, const float* __restrict__ Wh,
    short* __restrict__ W1T, short* __restrict__ W2T, short* __restrict__ WTl)
{
    int idx = blockIdx.x * 256 + threadIdx.x;   // 0 .. 131071
    if (idx < 192 * 256) {
        int j = idx >> 8, k = idx & 255;
        W1T[idx] = f2b(W1[k * H_ + j]);
    }
    if (idx < 128 * 192) {
        int j = idx / 192, k = idx - j * 192;
        W2T[idx] = f2b(W2[k * D_ + j]);
    }
    if (idx < 512 * 256) {
        int p = idx >> 8, k = idx & 255;
        int w = p >> 6, g = (p >> 4) & 3, jj = p & 15;
        int jo = g * 128 + w * 16 + jj;
        float v = (k < 128) ? Wx[k * 512 + jo] : Wh[(k - 128) * 512 + jo];
        WTl[idx] = f2b(v);
    }
}

// ---------------------------------------------------------------------------
// Table encoder v5: persistent blocks, raw barriers (no vmcnt drain in loop).
// grid 256 x 512 threads (8 waves), 16 b's per block, 32-row chunks,
// double-buffered LDS stage, register prefetch of next chunk.
// Wave (wr = w>>2, ww = w&3): rows [wr*16..+16), GEMM1 cols [ww*48..+48),
// GEMM2 cols [ww*32..+32).
// ---------------------------------------------------------------------------
__global__ __launch_bounds__(512) __attribute__((amdgpu_waves_per_eu(1, 2)))
void table_kernel(
    const float* __restrict__ header, const float* __restrict__ tword,
    const float* __restrict__ masks, const int* __restrict__ num_cols,
    const short* __restrict__ W1T, const float* __restrict__ b1,
    const short* __restrict__ W2T, const float* __restrict__ b2,
    float* __restrict__ te_out)
{
    const int bb0 = blockIdx.x * 16;
    const int tid = threadIdx.x;
    const int w   = tid >> 6;
    const int l   = tid & 63;
    const int lg  = l >> 4;
    const int ln  = l & 15;
    const int ww  = w & 3;
    const int wr  = w >> 2;

    __shared__ __align__(16) short flat_s[2][32 * 256];  // 2 x 16 KB, swizzled
    __shared__ __align__(16) short h_s[32 * 192];        // 12 KB, swizzled
    __shared__ float msk_s[16][64];                      // 4 KB
    __shared__ float ncol_s[16];
    __shared__ float redv[8][128];                       // 4 KB
    __shared__ float redq[2];

    // ---- resident weights (pinned)
    bf16x8 bw1[3][8];
    float bias1[3];
    #pragma unroll
    for (int ct = 0; ct < 3; ++ct) {
        int j = ww * 48 + ct * 16 + ln;
        bias1[ct] = b1[j];
        #pragma unroll
        for (int ks = 0; ks < 8; ++ks)
            bw1[ct][ks] = *(const bf16x8*)&W1T[j * 256 + ks * 32 + lg * 8];
    }
    bf16x8 bw2[2][6];
    float bias2[2];
    #pragma unroll
    for (int ct = 0; ct < 2; ++ct) {
        int j = ww * 32 + ct * 16 + ln;
        bias2[ct] = b2[j];
        #pragma unroll
        for (int ks = 0; ks < 6; ++ks)
            bw2[ct][ks] = *(const bf16x8*)&W2T[j * 192 + ks * 32 + lg * 8];
    }
    #pragma unroll
    for (int ct = 0; ct < 3; ++ct) {
        KEEP(bias1[ct]);
        #pragma unroll
        for (int ks = 0; ks < 8; ++ks) KEEP(bw1[ct][ks]);
    }
    #pragma unroll
    for (int ct = 0; ct < 2; ++ct) {
        KEEP(bias2[ct]);
        #pragma unroll
        for (int ks = 0; ks < 6; ++ks) KEEP(bw2[ct][ks]);
    }

    // ---- preload all masks + num_cols for the 16 b's (keeps main loop free
    //      of extra global loads that would order-block pf's vmcnt)
    {
        int i0 = tid * 2;                       // 1024 floats total
        *(float2*)&((float*)msk_s)[i0] = *(const float2*)&masks[(size_t)bb0 * C_ + i0];
        if (tid < 16) ncol_s[tid] = (float)num_cols[bb0 + tid];
    }
    __syncthreads();   // one full barrier pre-loop (nothing to preserve yet)

    // ---- prefetch: 4 float4 per thread = one 32-row fp32 chunk
    float4 pf[4];
    auto issue = [&](int cc) {
        int b    = bb0 + (cc >> 1);
        int row0 = (cc & 1) * 32;
        #pragma unroll
        for (int i = 0; i < 4; ++i) {
            int idx = i * 512 + tid;         // 0..2047 float4 slots
            int r   = idx >> 6;              // 0..31
            int c   = idx & 63;              // float4 col
            const float* src = (c < 32)
                ? &header[((size_t)b * C_ + row0 + r) * D_ + c * 4]
                : &tword [((size_t)b * C_ + row0 + r) * D_ + (c - 32) * 4];
            pf[i] = *(const float4*)src;
        }
    };
    issue(0);

    float csum0 = 0.f, csum1 = 0.f;

    for (int cc = 0; cc < 32; ++cc) {
        const int bi   = cc >> 1;
        const int half = cc & 1;
        char* fbuf = (char*)flat_s[cc & 1];

        // (a) write prefetched chunk -> flat_s (bf16, swizzled)
        //     (compiler inserts the vmcnt wait for pf HERE, after a full
        //      chunk of compute has covered the HBM latency)
        #pragma unroll
        for (int i = 0; i < 4; ++i) {
            int idx = i * 512 + tid;
            int r   = idx >> 6;
            int c   = idx & 63;
            uint2 p;
            p.x = cvt_pk_bf16(pf[i].x, pf[i].y);
            p.y = cvt_pk_bf16(pf[i].z, pf[i].w);
            *(uint2*)(fbuf + r * 512 + ((c * 8) ^ ((r & 7) << 4))) = p;
        }
        // (b) issue next chunk's loads; they stay in flight across the
        //     raw barriers below (no vmcnt drain in this loop)
        if (cc + 1 < 32) issue(cc + 1);
        wg_barrier();   // (c) flat ready

        // ---- GEMM1: rows wr*16+ln, cols ww*48..+48 (streamed A-frags)
        {
            int row = wr * 16 + ln;
            f32x4 acc[3];
            #pragma unroll
            for (int ct = 0; ct < 3; ++ct)
                acc[ct] = (f32x4){bias1[ct], bias1[ct], bias1[ct], bias1[ct]};
            #pragma unroll
            for (int ks = 0; ks < 8; ++ks) {
                bf16x8 a = *(const bf16x8*)(fbuf + row * 512 +
                                            ((ks * 64 + lg * 16) ^ ((row & 7) << 4)));
                #pragma unroll
                for (int ct = 0; ct < 3; ++ct)
                    acc[ct] = __builtin_amdgcn_mfma_f32_16x16x32_bf16(a, bw1[ct][ks], acc[ct], 0, 0, 0);
            }
            #pragma unroll
            for (int ct = 0; ct < 3; ++ct) {
                int col = ww * 48 + ct * 16 + ln;
                #pragma unroll
                for (int reg = 0; reg < 4; ++reg) {
                    int orow = wr * 16 + lg * 4 + reg;
                    *(short*)((char*)h_s + orow * 384 + ((col * 2) ^ ((orow & 7) << 4))) =
                        f2b(fmaxf(acc[ct][reg], 0.f));
                }
            }
        }
        wg_barrier();   // (e) h ready

        // ---- GEMM2 + fused mask*column-sum (streamed A-frags)
        {
            int row = wr * 16 + ln;
            f32x4 acc2[2];
            #pragma unroll
            for (int ct = 0; ct < 2; ++ct)
                acc2[ct] = (f32x4){bias2[ct], bias2[ct], bias2[ct], bias2[ct]};
            #pragma unroll
            for (int ks = 0; ks < 6; ++ks) {
                bf16x8 a = *(const bf16x8*)((char*)h_s + row * 384 +
                                            ((ks * 64 + lg * 16) ^ ((row & 7) << 4)));
                #pragma unroll
                for (int ct = 0; ct < 2; ++ct)
                    acc2[ct] = __builtin_amdgcn_mfma_f32_16x16x32_bf16(a, bw2[ct][ks], acc2[ct], 0, 0, 0);
            }
            #pragma unroll
            for (int reg = 0; reg < 4; ++reg) {
                int crow = half * 32 + wr * 16 + lg * 4 + reg;
                float m = msk_s[bi][crow];
                csum0 = fmaf(fmaxf(acc2[0][reg], 0.f), m, csum0);
                csum1 = fmaf(fmaxf(acc2[1][reg], 0.f), m, csum1);
            }
        }

        // ---- end of b: cross-wave reduce, l2norm, store
        if (half == 1) {
            #pragma unroll
            for (int s = 16; s < 64; s <<= 1) {
                csum0 += __shfl_xor(csum0, s, 64);
                csum1 += __shfl_xor(csum1, s, 64);
            }
            if (l < 16) {
                redv[w][ww * 32 + ln]      = csum0;
                redv[w][ww * 32 + 16 + ln] = csum1;
            }
            wg_barrier();
            float v = 0.f;
            if (tid < 128) {
                int j   = tid;
                int wwj = j >> 5;
                v = (redv[wwj][j] + redv[wwj + 4][j]) / ncol_s[bi];
                float s = v * v;
                #pragma unroll
                for (int sh = 1; sh < 64; sh <<= 1) s += __shfl_xor(s, sh, 64);
                if (l == 0) redq[w] = s;
            }
            wg_barrier();
            if (tid < 128) {
                float inv = rsqrtf(fmaxf(redq[0] + redq[1], 1e-12f));
                te_out[(size_t)(bb0 + bi) * D_ + tid] = v * inv;
            }
            csum0 = 0.f; csum1 = 0.f;
        }
    }
}

// ---------------------------------------------------------------------------
// LSTM v5: 256 blocks x 512 threads, 16 rows/block, raw barriers so the
// x_{t+1} prefetch stays in flight across the per-step barrier.
// ---------------------------------------------------------------------------
__global__ __launch_bounds__(512) __attribute__((amdgpu_waves_per_eu(1, 2)))
void lstm_kernel(
    const float* __restrict__ q, const int* __restrict__ lengths,
    const short* __restrict__ WTl, const float* __restrict__ bl,
    float* __restrict__ qe_out)
{
    const int tid = threadIdx.x;
    const int b0  = blockIdx.x * 16;
    const int w   = tid >> 6;
    const int l   = tid & 63;
    const int lg  = l >> 4;
    const int ln  = l & 15;       // batch row within block
    const int d0  = w * 16 + lg * 4;

    __shared__ __align__(16) short xh[2][16 * 256];  // 2 x 8 KB, swizzled
    __shared__ float red8[8][16];

    // W fragments resident across all timesteps (pinned)
    bf16x8 wf[4][8];
    #pragma unroll
    for (int g = 0; g < 4; ++g)
        #pragma unroll
        for (int ks = 0; ks < 8; ++ks)
            wf[g][ks] = *(const bf16x8*)&WTl[(w * 64 + g * 16 + ln) * 256 + ks * 32 + lg * 8];
    float bias[4][4];
    #pragma unroll
    for (int g = 0; g < 4; ++g)
        #pragma unroll
        for (int reg = 0; reg < 4; ++reg)
            bias[g][reg] = bl[g * 128 + d0 + reg];
    #pragma unroll
    for (int g = 0; g < 4; ++g) {
        #pragma unroll
        for (int ks = 0; ks < 8; ++ks) KEEP(wf[g][ks]);
        #pragma unroll
        for (int reg = 0; reg < 4; ++reg) KEEP(bias[g][reg]);
    }

    float creg[4] = {0.f, 0.f, 0.f, 0.f};
    float hreg[4] = {0.f, 0.f, 0.f, 0.f};
    const int len = lengths[b0 + ln];
    const int sr = tid >> 5, sc = tid & 31;

    // prefetch x_0
    float4 qv = *(const float4*)&q[((size_t)(b0 + sr) * LQ_ + 0) * D_ + sc * 4];

    for (int t = 0; t < LQ_; ++t) {
        char* buf = (char*)xh[t & 1];
        // stage x_t from prefetched regs
        uint2 px; px.x = cvt_pk_bf16(qv.x, qv.y); px.y = cvt_pk_bf16(qv.z, qv.w);
        *(uint2*)(buf + sr * 512 + ((sc * 8) ^ ((sr & 7) << 4))) = px;
        // write h(t-1)
        uint2 ph; ph.x = cvt_pk_bf16(hreg[0], hreg[1]); ph.y = cvt_pk_bf16(hreg[2], hreg[3]);
        *(uint2*)(buf + ln * 512 + ((256 + d0 * 2) ^ ((ln & 7) << 4))) = ph;
        // prefetch x_{t+1}: stays in flight across the raw barrier + MFMA
        if (t + 1 < LQ_)
            qv = *(const float4*)&q[((size_t)(b0 + sr) * LQ_ + (t + 1)) * D_ + sc * 4];
        wg_barrier();

        f32x4 acc[4];
        #pragma unroll
        for (int g = 0; g < 4; ++g)
            acc[g] = (f32x4){bias[g][0], bias[g][1], bias[g][2], bias[g][3]};
        #pragma unroll
        for (int ks = 0; ks < 8; ++ks) {
            bf16x8 xf = *(const bf16x8*)(buf + ln * 512 + ((ks * 64 + lg * 16) ^ ((ln & 7) << 4)));
            #pragma unroll
            for (int g = 0; g < 4; ++g)
                acc[g] = __builtin_amdgcn_mfma_f32_16x16x32_bf16(wf[g][ks], xf, acc[g], 0, 0, 0);
        }

        bool live = (t < len);
        #pragma unroll
        for (int reg = 0; reg < 4; ++reg) {
            float iv = sigm(acc[0][reg]);
            float fv = sigm(acc[1][reg]);
            float gv = fmaxf(acc[2][reg], 0.f);
            float ov = sigm(acc[3][reg]);
            float cn = fmaf(fv, creg[reg], iv * gv);
            float hn = ov * fmaxf(cn, 0.f);
            if (live) { creg[reg] = cn; hreg[reg] = hn; }
        }
    }

    // l2norm per batch row
    float sq = 0.f;
    #pragma unroll
    for (int reg = 0; reg < 4; ++reg) sq = fmaf(hreg[reg], hreg[reg], sq);
    sq += __shfl_xor(sq, 16, 64);
    sq += __shfl_xor(sq, 32, 64);
    if (l < 16) red8[w][ln] = sq;
    wg_barrier();
    float tot = 0.f;
    #pragma unroll
    for (int ww = 0; ww < 8; ++ww) tot += red8[ww][ln];
    float inv = rsqrtf(fmaxf(tot, 1e-12f));
    float4 o;
    o.x = hreg[0] * inv; o.y = hreg[1] * inv; o.z = hreg[2] * inv; o.w = hreg[3] * inv;
    *(float4*)&qe_out[(size_t)(b0 + ln) * D_ + d0] = o;
}

// ---------------------------------------------------------------------------
// Loss: 64 blocks x 64 threads, 1 sample per thread.
// ---------------------------------------------------------------------------
__global__ __launch_bounds__(64) void loss_kernel(
    const float* __restrict__ te, const float* __restrict__ qe,
    const float* __restrict__ labels, float* __restrict__ partial)
{
    const int tid = threadIdx.x;
    const int b   = blockIdx.x * 64 + tid;
    float dsum = 0.f;
    #pragma unroll 8
    for (int k4 = 0; k4 < 32; ++k4) {
        float4 a = *(const float4*)&qe[(size_t)b * D_ + k4 * 4];
        float4 c = *(const float4*)&te[(size_t)b * D_ + k4 * 4];
        float dx = a.x - c.x, dy = a.y - c.y, dz = a.z - c.z, dw = a.w - c.w;
        dsum += dx * dx + dy * dy + dz * dz + dw * dw;
    }
    float lab = labels[b];
    float ds  = sqrtf(dsum);
    float ml  = fmaxf(0.f, 1.f - ds);
    float loss = lab * dsum + (1.f - lab) * ml * ml;
    #pragma unroll
    for (int s = 32; s > 0; s >>= 1) loss += __shfl_xor(loss, s, 64);
    if (tid == 0) partial[blockIdx.x] = loss;
}

__global__ void final_kernel(const float* __restrict__ partial, float* __restrict__ out)
{
    const int tid = threadIdx.x;   // 64 threads
    float v = partial[tid];
    #pragma unroll
    for (int s = 32; s > 0; s >>= 1) v += __shfl_xor(v, s, 64);
    if (tid == 0) out[0] = 0.5f * v / (float)B_;
}

// ---------------------------------------------------------------------------
extern "C" void kernel_launch(void* const* d_in, const int* in_sizes, int n_in,
                              void* d_out, int out_size, void* d_ws, size_t ws_size,
                              hipStream_t stream)
{
    const float* q      = (const float*)d_in[0];
    const int*   qlen   = (const int*)d_in[1];
    const float* header = (const float*)d_in[2];
    const float* tword  = (const float*)d_in[3];
    const int*   ncols  = (const int*)d_in[4];
    const float* masks  = (const float*)d_in[5];
    const float* labels = (const float*)d_in[6];
    const float* W1     = (const float*)d_in[7];
    const float* b1     = (const float*)d_in[8];
    const float* W2     = (const float*)d_in[9];
    const float* b2     = (const float*)d_in[10];
    const float* Wx     = (const float*)d_in[11];
    const float* Wh     = (const float*)d_in[12];
    const float* bl     = (const float*)d_in[13];
    float* out = (float*)d_out;

    float* te      = (float*)d_ws;
    float* qe      = te + (size_t)B_ * D_;
    float* partial = qe + (size_t)B_ * D_;
    short* W1T     = (short*)(partial + 64);          // 192*256
    short* W2T     = W1T + 192 * 256;                 // 128*192
    short* WTl     = W2T + 128 * 192;                 // 512*256

    prep_kernel<<<512, 256, 0, stream>>>(W1, W2, Wx, Wh, W1T, W2T, WTl);
    table_kernel<<<B_ / 16, 512, 0, stream>>>(header, tword, masks, ncols, W1T, b1, W2T, b2, te);
    lstm_kernel<<<B_ / 16, 512, 0, stream>>>(q, qlen, WTl, bl, qe);
    loss_kernel<<<B_ / 64, 64, 0, stream>>>(te, qe, labels, partial);
    final_kernel<<<1, 64, 0, stream>>>(partial, out);
}